// Round 1
// baseline (42.582 us; speedup 1.0000x reference)
//
#include <hip/hip_runtime.h>
#include <hip/hip_bf16.h>

#define NUSERS 8192
#define HIDDEN 64
#define SIGMA2_INV (1.0f / (1.5f * 1.5f))
#define DIFF_COEFF 0.1f

__global__ __launch_bounds__(256) void stress_pde_kernel(
    const float* __restrict__ t,
    const float* __restrict__ S,
    const float* __restrict__ adj,
    const float* __restrict__ W1,   // (2, 64) row-major
    const float* __restrict__ b1,   // (64,)
    const float* __restrict__ W2,   // (64, 1)
    const float* __restrict__ b2,   // (1,)
    float* __restrict__ out)        // (8192,)
{
    const int row = blockIdx.x;
    const float Si = S[row];

    const float4* __restrict__ arow =
        reinterpret_cast<const float4*>(adj + (size_t)row * NUSERS);
    const float4* __restrict__ S4 = reinterpret_cast<const float4*>(S);

    // ---- diffusion: sum_j adj[i][j] * d * exp(-d^2/sigma^2), d = S[j]-S[i]
    float acc = 0.0f;
    #pragma unroll 4
    for (int j4 = threadIdx.x; j4 < NUSERS / 4; j4 += 256) {
        float4 a = arow[j4];
        float4 s = S4[j4];
        float d0 = s.x - Si;
        float d1 = s.y - Si;
        float d2 = s.z - Si;
        float d3 = s.w - Si;
        acc += a.x * d0 * __expf(-d0 * d0 * SIGMA2_INV);
        acc += a.y * d1 * __expf(-d1 * d1 * SIGMA2_INV);
        acc += a.z * d2 * __expf(-d2 * d2 * SIGMA2_INV);
        acc += a.w * d3 * __expf(-d3 * d3 * SIGMA2_INV);
    }
    // NOTE: j==row term has d=0 -> contributes 0, so diagonal zeroing is free.

    // wave (64-lane) reduce
    #pragma unroll
    for (int off = 32; off > 0; off >>= 1)
        acc += __shfl_down(acc, off, 64);

    __shared__ float wave_sums[4];
    const int wid = threadIdx.x >> 6;
    const int lane = threadIdx.x & 63;
    if (lane == 0) wave_sums[wid] = acc;

    // ---- reaction MLP: h_k = tanh(Si*W1[0][k] + t*W1[1][k] + b1[k]); r = h@W2 + b2
    __shared__ float hterm[HIDDEN];
    if (threadIdx.x < HIDDEN) {
        int k = threadIdx.x;
        float h = tanhf(Si * W1[k] + t[0] * W1[HIDDEN + k] + b1[k]);
        hterm[k] = h * W2[k];
    }
    __syncthreads();

    if (threadIdx.x == 0) {
        float diffusion = DIFF_COEFF *
            (wave_sums[0] + wave_sums[1] + wave_sums[2] + wave_sums[3]);
        float reaction = b2[0];
        #pragma unroll
        for (int k = 0; k < HIDDEN; ++k) reaction += hterm[k];
        out[row] = reaction + diffusion;
    }
}

extern "C" void kernel_launch(void* const* d_in, const int* in_sizes, int n_in,
                              void* d_out, int out_size, void* d_ws, size_t ws_size,
                              hipStream_t stream) {
    const float* t   = (const float*)d_in[0];
    const float* S   = (const float*)d_in[1];
    const float* adj = (const float*)d_in[2];
    const float* W1  = (const float*)d_in[3];
    const float* b1  = (const float*)d_in[4];
    const float* W2  = (const float*)d_in[5];
    const float* b2  = (const float*)d_in[6];
    float* out = (float*)d_out;

    stress_pde_kernel<<<NUSERS, 256, 0, stream>>>(t, S, adj, W1, b1, W2, b2, out);
}